// Round 1
// baseline (2473.916 us; speedup 1.0000x reference)
//
#include <hip/hip_runtime.h>
#include <cstddef>

#define FN_ 100000
#define V_  50000
#define B_  8
#define NCOL (B_ * FN_)   // 800000, divisible by 64

struct Ptrs { const void* p[33]; };

// Fold eval-mode BN (+ optional post-relu scale `mul`, valid since mul>0) into
// a per-output-row (scale, shift):  out = relu( dot*sc + sh )
__device__ __forceinline__ void bn_fold(const float* __restrict__ b,
                                        const float* __restrict__ g,
                                        const float* __restrict__ bt,
                                        const float* __restrict__ m,
                                        const float* __restrict__ v,
                                        int o, float mul, float& sc, float& sh) {
  float s = g[o] * rsqrtf(v[o] + 1e-5f);
  sc = s * mul;
  sh = ((b[o] - m[o]) * s + bt[o]) * mul;
}

__global__ __launch_bounds__(256) void sd_fused(Ptrs in, float* __restrict__ out)
{
  const float* __restrict__ centers = (const float*)in.p[0];
  const float* __restrict__ verts   = (const float*)in.p[1];
  const int*   __restrict__ faces   = (const int*)in.p[2];
  const float* __restrict__ cw1 = (const float*)in.p[3];
  const float* __restrict__ cb1 = (const float*)in.p[4];
  const float* __restrict__ c1g = (const float*)in.p[5];
  const float* __restrict__ c1bt= (const float*)in.p[6];
  const float* __restrict__ c1m = (const float*)in.p[7];
  const float* __restrict__ c1v = (const float*)in.p[8];
  const float* __restrict__ cw2 = (const float*)in.p[9];
  const float* __restrict__ cb2 = (const float*)in.p[10];
  const float* __restrict__ c2g = (const float*)in.p[11];
  const float* __restrict__ c2bt= (const float*)in.p[12];
  const float* __restrict__ c2m = (const float*)in.p[13];
  const float* __restrict__ c2v = (const float*)in.p[14];
  const float* __restrict__ vw1 = (const float*)in.p[15];
  const float* __restrict__ vb1 = (const float*)in.p[16];
  const float* __restrict__ v1g = (const float*)in.p[17];
  const float* __restrict__ v1bt= (const float*)in.p[18];
  const float* __restrict__ v1m = (const float*)in.p[19];
  const float* __restrict__ v1v = (const float*)in.p[20];
  const float* __restrict__ vw2 = (const float*)in.p[21];
  const float* __restrict__ vb2 = (const float*)in.p[22];
  const float* __restrict__ v2g = (const float*)in.p[23];
  const float* __restrict__ v2bt= (const float*)in.p[24];
  const float* __restrict__ v2m = (const float*)in.p[25];
  const float* __restrict__ v2v = (const float*)in.p[26];
  const float* __restrict__ sw  = (const float*)in.p[27];
  const float* __restrict__ sb  = (const float*)in.p[28];
  const float* __restrict__ s1g = (const float*)in.p[29];
  const float* __restrict__ s1bt= (const float*)in.p[30];
  const float* __restrict__ s1m = (const float*)in.p[31];
  const float* __restrict__ s1v = (const float*)in.p[32];

  __shared__ float xs[12][64];    // input channels: 0-8 = v0,v1,v2 xyz ; 9-11 = center xyz
  __shared__ float hs[64][64];    // hidden layer-1 activations (one head at a time)
  __shared__ float cv[128][64];   // rows 0-63 cfeat, 64-127 vfeat

  const int tid  = threadIdx.x;
  const int lane = tid & 63;
  // readfirstlane forces wave-uniformity so all weight addresses become SGPR
  // (s_load + v_fmac with scalar operand -> no per-FMA vector-memory traffic)
  const int w  = __builtin_amdgcn_readfirstlane(tid >> 6);
  const int ob = w * 16;                       // this wave's 16 output rows

  const unsigned colg = blockIdx.x * 64u + (unsigned)lane;   // global column
  const unsigned b = colg / FN_;
  const unsigned f = colg - b * FN_;

  // ---- gather: waves 0-2 fetch corner verts, wave 3 fetches centers ----
  if (w < 3) {
    int vi = faces[(size_t)colg * 3 + w];
    const float* vp = verts + ((size_t)b * V_ + (size_t)vi) * 3;
    xs[w*3+0][lane] = vp[0];
    xs[w*3+1][lane] = vp[1];
    xs[w*3+2][lane] = vp[2];
  } else {
#pragma unroll
    for (int k = 0; k < 3; ++k)
      xs[9+k][lane] = centers[((size_t)b*3 + k) * FN_ + f];
  }
  __syncthreads();

  // ---- L1 center: xs[9..11] -> hs  (K=3) ----
#pragma unroll
  for (int oo = 0; oo < 16; oo += 8) {
    float acc[8];
#pragma unroll
    for (int r = 0; r < 8; ++r) acc[r] = 0.f;
#pragma unroll
    for (int c = 0; c < 3; ++c) {
      float s = xs[9+c][lane];
#pragma unroll
      for (int r = 0; r < 8; ++r) acc[r] += cw1[(ob+oo+r)*3 + c] * s;
    }
#pragma unroll
    for (int r = 0; r < 8; ++r) {
      float sc, sh; bn_fold(cb1, c1g, c1bt, c1m, c1v, ob+oo+r, 1.f, sc, sh);
      hs[ob+oo+r][lane] = fmaxf(fmaf(acc[r], sc, sh), 0.f);
    }
  }
  __syncthreads();

  // ---- L2 center: hs -> cv[0..63]  (K=64) ----
#pragma unroll
  for (int oo = 0; oo < 16; oo += 8) {
    float acc[8];
#pragma unroll
    for (int r = 0; r < 8; ++r) acc[r] = 0.f;
#pragma unroll
    for (int c = 0; c < 64; ++c) {
      float s = hs[c][lane];
#pragma unroll
      for (int r = 0; r < 8; ++r) acc[r] += cw2[(ob+oo+r)*64 + c] * s;
    }
#pragma unroll
    for (int r = 0; r < 8; ++r) {
      float sc, sh; bn_fold(cb2, c2g, c2bt, c2m, c2v, ob+oo+r, 1.f, sc, sh);
      cv[ob+oo+r][lane] = fmaxf(fmaf(acc[r], sc, sh), 0.f);
    }
  }
  __syncthreads();   // hs free for edge reuse

  // ---- vertex branch: 3 edges share vw1/vw2; relu(y)/3 == relu(y/3) fold ----
  float vf[16];
#pragma unroll
  for (int i = 0; i < 16; ++i) vf[i] = 0.f;

  for (int e = 0; e < 3; ++e) {
    // L1 edge: channels (e*3+c)%9 -> hs  (K=6)
#pragma unroll
    for (int oo = 0; oo < 16; oo += 8) {
      float acc[8];
#pragma unroll
      for (int r = 0; r < 8; ++r) acc[r] = 0.f;
#pragma unroll
      for (int c = 0; c < 6; ++c) {
        float s = xs[(e*3 + c) % 9][lane];
#pragma unroll
        for (int r = 0; r < 8; ++r) acc[r] += vw1[(ob+oo+r)*6 + c] * s;
      }
#pragma unroll
      for (int r = 0; r < 8; ++r) {
        float sc, sh; bn_fold(vb1, v1g, v1bt, v1m, v1v, ob+oo+r, 1.f, sc, sh);
        hs[ob+oo+r][lane] = fmaxf(fmaf(acc[r], sc, sh), 0.f);
      }
    }
    __syncthreads();

    // L2 edge: hs -> vf regs (K=64), epilogue scaled by 1/3
#pragma unroll
    for (int oo = 0; oo < 16; oo += 8) {
      float acc[8];
#pragma unroll
      for (int r = 0; r < 8; ++r) acc[r] = 0.f;
#pragma unroll
      for (int c = 0; c < 64; ++c) {
        float s = hs[c][lane];
#pragma unroll
        for (int r = 0; r < 8; ++r) acc[r] += vw2[(ob+oo+r)*64 + c] * s;
      }
#pragma unroll
      for (int r = 0; r < 8; ++r) {
        float sc, sh; bn_fold(vb2, v2g, v2bt, v2m, v2v, ob+oo+r, 1.f/3.f, sc, sh);
        vf[oo+r] += fmaxf(fmaf(acc[r], sc, sh), 0.f);
      }
    }
    __syncthreads();   // hs consumed; safe to overwrite next edge
  }

  // vfeat -> cv rows 64..127
#pragma unroll
  for (int i = 0; i < 16; ++i) cv[64 + ob + i][lane] = vf[i];
  __syncthreads();

  // ---- L3: cv (128ch) -> out  (K=128) ----
#pragma unroll
  for (int oo = 0; oo < 16; oo += 8) {
    float acc[8];
#pragma unroll
    for (int r = 0; r < 8; ++r) acc[r] = 0.f;
#pragma unroll
    for (int c = 0; c < 128; ++c) {
      float s = cv[c][lane];
#pragma unroll
      for (int r = 0; r < 8; ++r) acc[r] += sw[(ob+oo+r)*128 + c] * s;
    }
#pragma unroll
    for (int r = 0; r < 8; ++r) {
      float sc, sh; bn_fold(sb, s1g, s1bt, s1m, s1v, ob+oo+r, 1.f, sc, sh);
      int o = ob + oo + r;
      out[((size_t)b*64 + o) * FN_ + f] = fmaxf(fmaf(acc[r], sc, sh), 0.f);
    }
  }
}

extern "C" void kernel_launch(void* const* d_in, const int* in_sizes, int n_in,
                              void* d_out, int out_size, void* d_ws, size_t ws_size,
                              hipStream_t stream) {
  (void)in_sizes; (void)n_in; (void)out_size; (void)d_ws; (void)ws_size;
  Ptrs p;
  for (int i = 0; i < 33; ++i) p.p[i] = d_in[i];
  dim3 grid(NCOL / 64), block(256);
  hipLaunchKernelGGL(sd_fused, grid, block, 0, stream, p, (float*)d_out);
}

// Round 2
// 194.450 us; speedup vs baseline: 12.7226x; 12.7226x over previous
//
#include <hip/hip_runtime.h>
#include <cstddef>
#include <cstdint>

#define FN_ 100000
#define V_  50000
#define B_  8
#define NT  128                       // columns per block
#define NBLK (B_ * FN_ / NT)          // 6250

typedef _Float16 f16;
typedef f16   f16x8 __attribute__((ext_vector_type(8)));
typedef float f32x4 __attribute__((ext_vector_type(4)));

struct Ptrs { const void* p[33]; };

union Pk4 { f16 h[4]; uint2 u; };

__global__ __launch_bounds__(512) void sd_mfma(Ptrs in, float* __restrict__ out)
{
  const float* __restrict__ centers = (const float*)in.p[0];
  const float* __restrict__ verts   = (const float*)in.p[1];
  const int*   __restrict__ faces   = (const int*)in.p[2];
  const float* __restrict__ cw1 = (const float*)in.p[3];
  const float* __restrict__ cb1 = (const float*)in.p[4];
  const float* __restrict__ c1g = (const float*)in.p[5];
  const float* __restrict__ c1bt= (const float*)in.p[6];
  const float* __restrict__ c1m = (const float*)in.p[7];
  const float* __restrict__ c1v = (const float*)in.p[8];
  const float* __restrict__ cw2 = (const float*)in.p[9];
  const float* __restrict__ cb2 = (const float*)in.p[10];
  const float* __restrict__ c2g = (const float*)in.p[11];
  const float* __restrict__ c2bt= (const float*)in.p[12];
  const float* __restrict__ c2m = (const float*)in.p[13];
  const float* __restrict__ c2v = (const float*)in.p[14];
  const float* __restrict__ vw1 = (const float*)in.p[15];
  const float* __restrict__ vb1 = (const float*)in.p[16];
  const float* __restrict__ v1g = (const float*)in.p[17];
  const float* __restrict__ v1bt= (const float*)in.p[18];
  const float* __restrict__ v1m = (const float*)in.p[19];
  const float* __restrict__ v1v = (const float*)in.p[20];
  const float* __restrict__ vw2 = (const float*)in.p[21];
  const float* __restrict__ vb2 = (const float*)in.p[22];
  const float* __restrict__ v2g = (const float*)in.p[23];
  const float* __restrict__ v2bt= (const float*)in.p[24];
  const float* __restrict__ v2m = (const float*)in.p[25];
  const float* __restrict__ v2v = (const float*)in.p[26];
  const float* __restrict__ sw  = (const float*)in.p[27];
  const float* __restrict__ sb  = (const float*)in.p[28];
  const float* __restrict__ s1g = (const float*)in.p[29];
  const float* __restrict__ s1bt= (const float*)in.p[30];
  const float* __restrict__ s1m = (const float*)in.p[31];
  const float* __restrict__ s1v = (const float*)in.p[32];

  // Row strides in BYTES are all multiples of 16 (b128-aligned) and chosen so
  // 16 lanes reading consecutive rows hit >=8 distinct bank-quads (<=2-way, free).
  __shared__ f16  Xs [NT][40];     // [col][k]  k: 0-8 v0/v1/v2 xyz, 9-11 center, 12-31 zero pad (+8 stride pad)
  __shared__ f16  W1s[256][40];    // combined L1 weights [row][k<32]; rows 0-63 center, 64+64e edge e
  __shared__ f16  W2cs[64][72];    // c2 weights (BN-scale folded)
  __shared__ f16  W2vs[64][72];    // v2 weights (BN-scale and 1/3 folded)
  __shared__ f16  Wss[64][136];    // s  weights
  __shared__ f16  Hs [NT][264];    // activations, column-major [col][k]; L1 out k:0..255, later cv k:0..127
  __shared__ float scs[448], shs[448];  // folded BN scale/shift: 0-255 L1, 256 c2, 320 v2, 384 s

  const int tid  = threadIdx.x;
  const int lane = tid & 63;
  const int r15  = lane & 15;
  const int g4   = lane >> 4;
  const int wid  = __builtin_amdgcn_readfirstlane(tid >> 6);

  // ---------------- phase A1: gather X + compute BN scale/shift ----------------
  {
    int col = tid >> 2, p = tid & 3;
    unsigned colg = blockIdx.x * (unsigned)NT + (unsigned)col;
    unsigned b = colg / FN_;
    unsigned f = colg - b * FN_;
    if (p < 3) {
      int vi = faces[(size_t)colg * 3 + p];
      const float* vp = verts + ((size_t)b * V_ + (size_t)vi) * 3;
      Xs[col][p*3+0] = (f16)vp[0];
      Xs[col][p*3+1] = (f16)vp[1];
      Xs[col][p*3+2] = (f16)vp[2];
    } else {
#pragma unroll
      for (int k = 0; k < 3; ++k)
        Xs[col][9+k] = (f16)centers[((size_t)b*3 + k) * FN_ + f];
    }
    // zero k = 12..39 (28 entries, 7 per helper thread)
#pragma unroll
    for (int z = 0; z < 7; ++z) Xs[col][12 + p*7 + z] = (f16)0.f;
  }
  if (tid < 448) {
    const float *g, *v, *bb, *m, *bt; int o; float mul = 1.f;
    if (tid < 64)       { o = tid;      g=c1g; v=c1v; bb=cb1; m=c1m; bt=c1bt; }
    else if (tid < 256) { o = tid & 63; g=v1g; v=v1v; bb=vb1; m=v1m; bt=v1bt; }
    else if (tid < 320) { o = tid-256;  g=c2g; v=c2v; bb=cb2; m=c2m; bt=c2bt; }
    else if (tid < 384) { o = tid-320;  g=v2g; v=v2v; bb=vb2; m=v2m; bt=v2bt; mul = 1.f/3.f; }
    else                { o = tid-384;  g=s1g; v=s1v; bb=sb;  m=s1m; bt=s1bt; }
    float s = g[o] * rsqrtf(v[o] + 1e-5f);
    scs[tid] = s * mul;
    shs[tid] = ((bb[o] - m[o]) * s + bt[o]) * mul;
  }
  __syncthreads();

  // ---------------- phase A2a: zero W1s, fold dense weights ----------------
  for (int i = tid; i < 256*40/2; i += 512) ((uint32_t*)W1s)[i] = 0u;
  for (int i = tid; i < 4096; i += 512) { int o = i >> 6, c = i & 63;  W2cs[o][c] = (f16)(cw2[i] * scs[256+o]); }
  for (int i = tid; i < 4096; i += 512) { int o = i >> 6, c = i & 63;  W2vs[o][c] = (f16)(vw2[i] * scs[320+o]); }
  for (int i = tid; i < 8192; i += 512) { int o = i >> 7, c = i & 127; Wss [o][c] = (f16)(sw[i]  * scs[384+o]); }
  __syncthreads();

  // ---------------- phase A2b: scatter-fill combined L1 weights ----------------
  if (tid < 192) { int o = tid/3, c = tid - o*3; W1s[o][9+c] = (f16)(cw1[tid] * scs[o]); }
  for (int i = tid; i < 1152; i += 512) {
    int e = i / 384, r = i - e*384, o = r / 6, c = r - o*6;
    W1s[64 + e*64 + o][(3*e + c) % 9] = (f16)(vw1[r] * scs[64 + e*64 + o]);
  }
  __syncthreads();

  // ---------------- L1: [256 x 32pad] x [32pad x 128] -> Hs[col][0..255] ----------------
  {
    const int wm = wid >> 1;          // row group of 64 (== branch)
    const int wn = wid & 1;           // col group of 64
    f16x8 bfr[4];
#pragma unroll
    for (int tc = 0; tc < 4; ++tc)
      bfr[tc] = *(const f16x8*)&Xs[64*wn + 16*tc + r15][8*g4];
#pragma unroll
    for (int tr = 0; tr < 4; ++tr) {
      f16x8 a = *(const f16x8*)&W1s[64*wm + 16*tr + r15][8*g4];
#pragma unroll
      for (int tc = 0; tc < 4; ++tc) {
        f32x4 acc = {0.f, 0.f, 0.f, 0.f};
        acc = __builtin_amdgcn_mfma_f32_16x16x32_f16(a, bfr[tc], acc, 0, 0, 0);
        const int o0  = 64*wm + 16*tr + 4*g4;
        const int col = 64*wn + 16*tc + r15;
        Pk4 pk;
#pragma unroll
        for (int j = 0; j < 4; ++j) pk.h[j] = (f16)fmaxf(acc[j] + shs[o0+j], 0.f);
        *(uint2*)&Hs[col][o0] = pk.u;
      }
    }
  }
  __syncthreads();

  // ---------------- L2: center + 3 edges (M=64, K=64 each) ----------------
  const int wm2 = wid >> 2;           // row group of 32
  const int wn2 = wid & 3;            // col group of 32
  float cf[2][2][4];
  float vf[2][2][4];
#pragma unroll
  for (int a1 = 0; a1 < 2; ++a1)
#pragma unroll
    for (int a2 = 0; a2 < 2; ++a2)
#pragma unroll
      for (int j = 0; j < 4; ++j) vf[a1][a2][j] = 0.f;

#pragma unroll
  for (int br = 0; br < 4; ++br) {    // 0 = center, 1..3 = edges
    f32x4 acc[2][2];
#pragma unroll
    for (int tr = 0; tr < 2; ++tr)
#pragma unroll
      for (int tc = 0; tc < 2; ++tc) acc[tr][tc] = (f32x4){0.f,0.f,0.f,0.f};
#pragma unroll
    for (int s = 0; s < 2; ++s) {
      f16x8 a[2], bfr[2];
#pragma unroll
      for (int tr = 0; tr < 2; ++tr) {
        const f16* wsrc = (br == 0) ? &W2cs[32*wm2 + 16*tr + r15][32*s + 8*g4]
                                    : &W2vs[32*wm2 + 16*tr + r15][32*s + 8*g4];
        a[tr] = *(const f16x8*)wsrc;
      }
#pragma unroll
      for (int tc = 0; tc < 2; ++tc)
        bfr[tc] = *(const f16x8*)&Hs[32*wn2 + 16*tc + r15][64*br + 32*s + 8*g4];
#pragma unroll
      for (int tr = 0; tr < 2; ++tr)
#pragma unroll
        for (int tc = 0; tc < 2; ++tc)
          acc[tr][tc] = __builtin_amdgcn_mfma_f32_16x16x32_f16(a[tr], bfr[tc], acc[tr][tc], 0, 0, 0);
    }
#pragma unroll
    for (int tr = 0; tr < 2; ++tr)
#pragma unroll
      for (int tc = 0; tc < 2; ++tc)
#pragma unroll
        for (int j = 0; j < 4; ++j) {
          const int o = 32*wm2 + 16*tr + 4*g4 + j;
          if (br == 0) cf[tr][tc][j]  = fmaxf(acc[tr][tc][j] + shs[256+o], 0.f);
          else         vf[tr][tc][j] += fmaxf(acc[tr][tc][j] + shs[320+o], 0.f);
        }
  }
  __syncthreads();   // all Hs reads done; safe to overwrite k=0..127 with cv

#pragma unroll
  for (int tr = 0; tr < 2; ++tr)
#pragma unroll
    for (int tc = 0; tc < 2; ++tc) {
      const int o0  = 32*wm2 + 16*tr + 4*g4;
      const int col = 32*wn2 + 16*tc + r15;
      Pk4 pc, pv;
#pragma unroll
      for (int j = 0; j < 4; ++j) { pc.h[j] = (f16)cf[tr][tc][j]; pv.h[j] = (f16)vf[tr][tc][j]; }
      *(uint2*)&Hs[col][o0]      = pc.u;   // cfeat -> k 0..63
      *(uint2*)&Hs[col][64 + o0] = pv.u;   // vfeat -> k 64..127
    }
  __syncthreads();

  // ---------------- L3: [64 x 128] x [128 x cols] -> out ----------------
  {
    f32x4 acc[2][2];
#pragma unroll
    for (int tr = 0; tr < 2; ++tr)
#pragma unroll
      for (int tc = 0; tc < 2; ++tc) acc[tr][tc] = (f32x4){0.f,0.f,0.f,0.f};
#pragma unroll
    for (int s = 0; s < 4; ++s) {
      f16x8 a[2], bfr[2];
#pragma unroll
      for (int tr = 0; tr < 2; ++tr)
        a[tr] = *(const f16x8*)&Wss[32*wm2 + 16*tr + r15][32*s + 8*g4];
#pragma unroll
      for (int tc = 0; tc < 2; ++tc)
        bfr[tc] = *(const f16x8*)&Hs[32*wn2 + 16*tc + r15][32*s + 8*g4];
#pragma unroll
      for (int tr = 0; tr < 2; ++tr)
#pragma unroll
        for (int tc = 0; tc < 2; ++tc)
          acc[tr][tc] = __builtin_amdgcn_mfma_f32_16x16x32_f16(a[tr], bfr[tc], acc[tr][tc], 0, 0, 0);
    }
#pragma unroll
    for (int tr = 0; tr < 2; ++tr)
#pragma unroll
      for (int tc = 0; tc < 2; ++tc) {
        const unsigned colg = blockIdx.x * (unsigned)NT + 32*wn2 + 16*tc + r15;
        const unsigned b = colg / FN_;
        const unsigned f = colg - b * FN_;
#pragma unroll
        for (int j = 0; j < 4; ++j) {
          const int o = 32*wm2 + 16*tr + 4*g4 + j;
          out[((size_t)(b*64u + o)) * FN_ + f] = fmaxf(acc[tr][tc][j] + shs[384+o], 0.f);
        }
      }
  }
}

extern "C" void kernel_launch(void* const* d_in, const int* in_sizes, int n_in,
                              void* d_out, int out_size, void* d_ws, size_t ws_size,
                              hipStream_t stream) {
  (void)in_sizes; (void)n_in; (void)out_size; (void)d_ws; (void)ws_size;
  Ptrs p;
  for (int i = 0; i < 33; ++i) p.p[i] = d_in[i];
  hipLaunchKernelGGL(sd_mfma, dim3(NBLK), dim3(512), 0, stream, p, (float*)d_out);
}

// Round 3
// 98.023 us; speedup vs baseline: 25.2380x; 1.9837x over previous
//
#include <hip/hip_runtime.h>
#include <cstddef>
#include <cstdint>

#define FN_ 100000
#define V_  50000
#define B_  8
#define NT  128
#define NBLK (B_ * FN_ / NT)          // 6250

// d_ws layout (bytes): 48 weight tiles of 1 KB (fragment order), then shs f32[448]
//   tiles  0..15 : combined L1 weights (256x32, BN-scale folded, scatter layout)
//   tiles 16..23 : c2 weights (64x64)
//   tiles 24..31 : v2 weights (64x64, x1/3 folded)
//   tiles 32..47 : s  weights (64x128)
#define WS_SHS 49152                  // total ws use: 50944 bytes

typedef _Float16 f16;
typedef f16   f16x8 __attribute__((ext_vector_type(8)));
typedef float f32x4 __attribute__((ext_vector_type(4)));

struct Ptrs { const void* p[33]; };

union Pk4 { f16 h[4]; uint2 u; };
union Pk8 { f16 h[8]; uint4 u; };

// ---------------- prep: fold BN into f16 weights, fragment-ordered ----------------
__global__ __launch_bounds__(1024) void sd_prep(Ptrs in, f16* __restrict__ wsW,
                                                float* __restrict__ shsG)
{
  const float* __restrict__ cw1 = (const float*)in.p[3];
  const float* __restrict__ cb1 = (const float*)in.p[4];
  const float* __restrict__ c1g = (const float*)in.p[5];
  const float* __restrict__ c1bt= (const float*)in.p[6];
  const float* __restrict__ c1m = (const float*)in.p[7];
  const float* __restrict__ c1v = (const float*)in.p[8];
  const float* __restrict__ cw2 = (const float*)in.p[9];
  const float* __restrict__ cb2 = (const float*)in.p[10];
  const float* __restrict__ c2g = (const float*)in.p[11];
  const float* __restrict__ c2bt= (const float*)in.p[12];
  const float* __restrict__ c2m = (const float*)in.p[13];
  const float* __restrict__ c2v = (const float*)in.p[14];
  const float* __restrict__ vw1 = (const float*)in.p[15];
  const float* __restrict__ vb1 = (const float*)in.p[16];
  const float* __restrict__ v1g = (const float*)in.p[17];
  const float* __restrict__ v1bt= (const float*)in.p[18];
  const float* __restrict__ v1m = (const float*)in.p[19];
  const float* __restrict__ v1v = (const float*)in.p[20];
  const float* __restrict__ vw2 = (const float*)in.p[21];
  const float* __restrict__ vb2 = (const float*)in.p[22];
  const float* __restrict__ v2g = (const float*)in.p[23];
  const float* __restrict__ v2bt= (const float*)in.p[24];
  const float* __restrict__ v2m = (const float*)in.p[25];
  const float* __restrict__ v2v = (const float*)in.p[26];
  const float* __restrict__ sw  = (const float*)in.p[27];
  const float* __restrict__ sb  = (const float*)in.p[28];
  const float* __restrict__ s1g = (const float*)in.p[29];
  const float* __restrict__ s1bt= (const float*)in.p[30];
  const float* __restrict__ s1m = (const float*)in.p[31];
  const float* __restrict__ s1v = (const float*)in.p[32];

  __shared__ float scsL[448];
  const int tid = threadIdx.x;

  if (tid < 448) {
    const float *g, *v, *bb, *m, *bt; int o; float mul = 1.f;
    if (tid < 64)       { o = tid;      g=c1g; v=c1v; bb=cb1; m=c1m; bt=c1bt; }
    else if (tid < 256) { o = tid & 63; g=v1g; v=v1v; bb=vb1; m=v1m; bt=v1bt; }
    else if (tid < 320) { o = tid-256;  g=c2g; v=c2v; bb=cb2; m=c2m; bt=c2bt; }
    else if (tid < 384) { o = tid-320;  g=v2g; v=v2v; bb=vb2; m=v2m; bt=v2bt; mul = 1.f/3.f; }
    else                { o = tid-384;  g=s1g; v=s1v; bb=sb;  m=s1m; bt=s1bt; }
    float s = g[o] * rsqrtf(v[o] + 1e-5f);
    scsL[tid] = s * mul;
    shsG[tid] = ((bb[o] - m[o]) * s + bt[o]) * mul;
  }
  __syncthreads();

  // 48 tiles x 64 lanes; each unit produces 8 f16 (one 16B fragment slice)
  for (int u = tid; u < 3072; u += 1024) {
    const int t = u >> 6, l = u & 63, r15 = l & 15, g4 = l >> 4;
    Pk8 pk;
    if (t < 16) {                                   // L1 combined 256x32
      const int wm = t >> 2, tr = t & 3, row = 64*wm + 16*tr + r15;
#pragma unroll
      for (int j = 0; j < 8; ++j) {
        const int k = 8*g4 + j; float val = 0.f;
        if (wm == 0) { if (k >= 9 && k < 12) val = cw1[row*3 + (k-9)]; }
        else if (k < 9) {
          const int e = wm - 1, o = row - 64*wm, c = (k - 3*e + 9) % 9;
          if (c < 6) val = vw1[o*6 + c];
        }
        pk.h[j] = (f16)(val * scsL[row]);
      }
    } else if (t < 24) {                            // c2
      const int tt = t-16, rt = tt >> 1, s = tt & 1, row = 16*rt + r15;
#pragma unroll
      for (int j = 0; j < 8; ++j) { const int k = 32*s + 8*g4 + j;
        pk.h[j] = (f16)(cw2[row*64 + k] * scsL[256+row]); }
    } else if (t < 32) {                            // v2 (x 1/3)
      const int tt = t-24, rt = tt >> 1, s = tt & 1, row = 16*rt + r15;
#pragma unroll
      for (int j = 0; j < 8; ++j) { const int k = 32*s + 8*g4 + j;
        pk.h[j] = (f16)(vw2[row*64 + k] * scsL[320+row]); }
    } else {                                        // s (64x128)
      const int tt = t-32, rt = tt >> 2, s = tt & 3, row = 16*rt + r15;
#pragma unroll
      for (int j = 0; j < 8; ++j) { const int k = 32*s + 8*g4 + j;
        pk.h[j] = (f16)(sw[row*128 + k] * scsL[384+row]); }
    }
    *(uint4*)(wsW + (size_t)t*512 + l*8) = pk.u;
  }
}

// ---------------- main ----------------
__global__ __launch_bounds__(512, 4) void sd_main(const int* __restrict__ faces,
    const float* __restrict__ verts, const float* __restrict__ centers,
    const f16* __restrict__ wsW, const float* __restrict__ shsG,
    float* __restrict__ out)
{
  // Hs[col][k]: k 0..255 = L1 activations (later k 0..127 = cv), k 256..287 = X, 288..295 pad
  // stride 296 f16 = 148 dw ≡ 20 (mod 32) -> ~2-way bank aliasing (free per m136)
  __shared__ f16 Hs[NT][296];
  __shared__ float shsL[448];

  const int tid  = threadIdx.x;
  const int lane = tid & 63;
  const int r15  = lane & 15;
  const int g4   = lane >> 4;
  const int wid  = __builtin_amdgcn_readfirstlane(tid >> 6);

  if (tid < 448) shsL[tid] = shsG[tid];

  // gather X
  {
    const int col = tid >> 2, p = tid & 3;
    const unsigned colg = blockIdx.x * (unsigned)NT + (unsigned)col;
    const unsigned b = colg / FN_;
    const unsigned f = colg - b * FN_;
    if (p < 3) {
      const int vi = faces[(size_t)colg*3 + p];
      const float* vp = verts + ((size_t)b*V_ + (size_t)vi)*3;
      Hs[col][256 + p*3 + 0] = (f16)vp[0];
      Hs[col][256 + p*3 + 1] = (f16)vp[1];
      Hs[col][256 + p*3 + 2] = (f16)vp[2];
    } else {
#pragma unroll
      for (int k = 0; k < 3; ++k)
        Hs[col][265 + k] = (f16)centers[((size_t)b*3 + k)*FN_ + f];
    }
#pragma unroll
    for (int z = 0; z < 5; ++z) Hs[col][268 + p*5 + z] = (f16)0.f;
  }
  __syncthreads();

  const int wm2 = wid >> 2, wn2 = wid & 3;

  // prefetch L2-layer weight fragments (L2-cache-hot) to hide latency under L1
  f16x8 w2c[2][2], w2v[2][2];
#pragma unroll
  for (int tr = 0; tr < 2; ++tr)
#pragma unroll
    for (int s = 0; s < 2; ++s) {
      w2c[tr][s] = *(const f16x8*)(wsW + (size_t)(16 + (2*wm2+tr)*2 + s)*512 + lane*8);
      w2v[tr][s] = *(const f16x8*)(wsW + (size_t)(24 + (2*wm2+tr)*2 + s)*512 + lane*8);
    }

  // ---- L1: W1[256x32] x X[32x128] ----
  {
    const int wm = wid >> 1, wn = wid & 1;
    f16x8 bfr[4];
#pragma unroll
    for (int tc = 0; tc < 4; ++tc)
      bfr[tc] = *(const f16x8*)&Hs[64*wn + 16*tc + r15][256 + 8*g4];
#pragma unroll
    for (int tr = 0; tr < 4; ++tr) {
      const f16x8 a = *(const f16x8*)(wsW + (size_t)(wm*4 + tr)*512 + lane*8);
#pragma unroll
      for (int tc = 0; tc < 4; ++tc) {
        f32x4 acc = {0.f,0.f,0.f,0.f};
        acc = __builtin_amdgcn_mfma_f32_16x16x32_f16(a, bfr[tc], acc, 0,0,0);
        const int o0  = 64*wm + 16*tr + 4*g4;
        const int col = 64*wn + 16*tc + r15;
        const f32x4 sh = *(const f32x4*)&shsL[o0];
        Pk4 pk;
#pragma unroll
        for (int j = 0; j < 4; ++j) pk.h[j] = (f16)fmaxf(acc[j] + sh[j], 0.f);
        *(uint2*)&Hs[col][o0] = pk.u;
      }
    }
  }
  __syncthreads();

  // ---- L2: center (br=0) + 3 edges, K=64 each ----
  float cf[2][2][4], vf[2][2][4];
#pragma unroll
  for (int tr = 0; tr < 2; ++tr)
#pragma unroll
    for (int tc = 0; tc < 2; ++tc)
#pragma unroll
      for (int j = 0; j < 4; ++j) vf[tr][tc][j] = 0.f;

#pragma unroll
  for (int br = 0; br < 4; ++br) {
    f32x4 acc[2][2];
#pragma unroll
    for (int tr = 0; tr < 2; ++tr)
#pragma unroll
      for (int tc = 0; tc < 2; ++tc) acc[tr][tc] = (f32x4){0.f,0.f,0.f,0.f};
#pragma unroll
    for (int s = 0; s < 2; ++s) {
      const f16x8 b0 = *(const f16x8*)&Hs[32*wn2 +      r15][64*br + 32*s + 8*g4];
      const f16x8 b1 = *(const f16x8*)&Hs[32*wn2 + 16 + r15][64*br + 32*s + 8*g4];
#pragma unroll
      for (int tr = 0; tr < 2; ++tr) {
        const f16x8 a = br ? w2v[tr][s] : w2c[tr][s];
        acc[tr][0] = __builtin_amdgcn_mfma_f32_16x16x32_f16(a, b0, acc[tr][0], 0,0,0);
        acc[tr][1] = __builtin_amdgcn_mfma_f32_16x16x32_f16(a, b1, acc[tr][1], 0,0,0);
      }
    }
#pragma unroll
    for (int tr = 0; tr < 2; ++tr) {
      const int o0 = 32*wm2 + 16*tr + 4*g4;
      const f32x4 sh = br ? *(const f32x4*)&shsL[320+o0] : *(const f32x4*)&shsL[256+o0];
#pragma unroll
      for (int tc = 0; tc < 2; ++tc)
#pragma unroll
        for (int j = 0; j < 4; ++j) {
          if (br == 0) cf[tr][tc][j]  = fmaxf(acc[tr][tc][j] + sh[j], 0.f);
          else         vf[tr][tc][j] += fmaxf(acc[tr][tc][j] + sh[j], 0.f);
        }
    }
  }
  __syncthreads();      // all Hs reads done; safe to overwrite k 0..127 with cv

#pragma unroll
  for (int tr = 0; tr < 2; ++tr)
#pragma unroll
    for (int tc = 0; tc < 2; ++tc) {
      const int o0  = 32*wm2 + 16*tr + 4*g4;
      const int col = 32*wn2 + 16*tc + r15;
      Pk4 pc, pv;
#pragma unroll
      for (int j = 0; j < 4; ++j) { pc.h[j] = (f16)cf[tr][tc][j]; pv.h[j] = (f16)vf[tr][tc][j]; }
      *(uint2*)&Hs[col][o0]      = pc.u;    // cfeat k 0..63
      *(uint2*)&Hs[col][64 + o0] = pv.u;    // vfeat k 64..127
    }
  __syncthreads();

  // ---- L3: Ws[64x128] x cv[128x128] -> out ----
  {
    f32x4 acc[2][2];
#pragma unroll
    for (int tr = 0; tr < 2; ++tr)
#pragma unroll
      for (int tc = 0; tc < 2; ++tc) acc[tr][tc] = (f32x4){0.f,0.f,0.f,0.f};
#pragma unroll
    for (int s = 0; s < 4; ++s) {
      const f16x8 b0 = *(const f16x8*)&Hs[32*wn2 +      r15][32*s + 8*g4];
      const f16x8 b1 = *(const f16x8*)&Hs[32*wn2 + 16 + r15][32*s + 8*g4];
#pragma unroll
      for (int tr = 0; tr < 2; ++tr) {
        const f16x8 a = *(const f16x8*)(wsW + (size_t)(32 + (2*wm2+tr)*4 + s)*512 + lane*8);
        acc[tr][0] = __builtin_amdgcn_mfma_f32_16x16x32_f16(a, b0, acc[tr][0], 0,0,0);
        acc[tr][1] = __builtin_amdgcn_mfma_f32_16x16x32_f16(a, b1, acc[tr][1], 0,0,0);
      }
    }
#pragma unroll
    for (int tr = 0; tr < 2; ++tr)
#pragma unroll
      for (int tc = 0; tc < 2; ++tc) {
        const unsigned colg = blockIdx.x * (unsigned)NT + 32*wn2 + 16*tc + r15;
        const unsigned b = colg / FN_;
        const unsigned f = colg - b * FN_;
        const int o0 = 32*wm2 + 16*tr + 4*g4;
        const f32x4 sh = *(const f32x4*)&shsL[384 + o0];
#pragma unroll
        for (int j = 0; j < 4; ++j)
          out[((size_t)(b*64u + o0 + j))*FN_ + f] = fmaxf(acc[tr][tc][j] + sh[j], 0.f);
      }
  }
}

extern "C" void kernel_launch(void* const* d_in, const int* in_sizes, int n_in,
                              void* d_out, int out_size, void* d_ws, size_t ws_size,
                              hipStream_t stream) {
  (void)in_sizes; (void)n_in; (void)out_size; (void)ws_size;
  Ptrs p;
  for (int i = 0; i < 33; ++i) p.p[i] = d_in[i];
  f16*   wsW  = (f16*)d_ws;
  float* shsG = (float*)((char*)d_ws + WS_SHS);
  hipLaunchKernelGGL(sd_prep, dim3(1), dim3(1024), 0, stream, p, wsW, shsG);
  hipLaunchKernelGGL(sd_main, dim3(NBLK), dim3(512), 0, stream,
                     (const int*)d_in[2], (const float*)d_in[1], (const float*)d_in[0],
                     wsW, shsG, (float*)d_out);
}